// Round 12
// baseline (115.623 us; speedup 1.0000x reference)
//
#include <hip/hip_runtime.h>
#include <hip/hip_bf16.h>
#include <stdint.h>

// MSA: x[2,2048,1024] fp32, w_qkv[3072,1024], w_out[1024,1024] -> out[2,2048,1024] fp32
// Internal bf16 MFMA. B=2 T=2048 E=1024 H=16 D=64, SCALE=1/8.
// Q is pre-scaled by ALPHA = SCALE*log2(e) in the QKV epilogue; attn uses exp2 directly.

using u16 = uint16_t;
typedef __bf16 bf16x8 __attribute__((ext_vector_type(8)));
typedef float f32x4 __attribute__((ext_vector_type(4)));
typedef float f32x16 __attribute__((ext_vector_type(16)));
typedef unsigned short ushort8 __attribute__((ext_vector_type(8)));
typedef uint32_t u32x4 __attribute__((ext_vector_type(4)));
typedef unsigned int u32x2v __attribute__((ext_vector_type(2)));

#define DEV __device__ __forceinline__

typedef __attribute__((address_space(1))) void as1_void;
typedef __attribute__((address_space(3))) void as3_void;

DEV void async16(void* lds_uniform, const void* gsrc) {
    __builtin_amdgcn_global_load_lds((as1_void*)(gsrc), (as3_void*)(lds_uniform), 16, 0, 0);
}

DEV uint16_t f2bf(float x) {  // RNE fp32->bf16 (finite inputs)
    uint32_t u = __builtin_bit_cast(uint32_t, x);
    u += 0x7fffu + ((u >> 16) & 1u);
    return (uint16_t)(u >> 16);
}

DEV uint32_t pack2(float a, float b) {
    return (uint32_t)f2bf(a) | ((uint32_t)f2bf(b) << 16);
}

DEV uint32_t cvtpk(float lo, float hi) {  // v_cvt_pk_bf16_f32
    uint32_t r;
    asm("v_cvt_pk_bf16_f32 %0, %1, %2" : "=v"(r) : "v"(lo), "v"(hi));
    return r;
}

DEV float exp2r(float x) { return __builtin_amdgcn_exp2f(x); }  // raw v_exp_f32

// ---------------- fused fp32 -> bf16 cast for x, w_qkv, w_out ----------------
__global__ __launch_bounds__(256) void k_cvt3(const float* __restrict__ x,
                                              const float* __restrict__ wq,
                                              const float* __restrict__ wo,
                                              u16* __restrict__ xb,
                                              u16* __restrict__ wqb,
                                              u16* __restrict__ wob) {
    int i = blockIdx.x * 256 + threadIdx.x;  // 0 .. 1048575 (x8 elems)
    const float* in;
    u16* out;
    int j;
    if (i < 524288)       { in = x;  out = xb;  j = i; }
    else if (i < 917504)  { in = wq; out = wqb; j = i - 524288; }
    else                  { in = wo; out = wob; j = i - 917504; }
    const float4* p = (const float4*)in;
    float4 a = p[2 * (size_t)j], b = p[2 * (size_t)j + 1];
    ushort8 o;
    o[0] = f2bf(a.x); o[1] = f2bf(a.y); o[2] = f2bf(a.z); o[3] = f2bf(a.w);
    o[4] = f2bf(b.x); o[5] = f2bf(b.y); o[6] = f2bf(b.z); o[7] = f2bf(b.w);
    *(ushort8*)(out + 8 * (size_t)j) = o;
}

// ========= QKV GEMM: 128x192 tile, BK=32, 2 blocks/CU (LDS 40KB), 2-barrier/tile =====
// C[4096,3072] = xb * wqb^T. 512 blocks, 8 waves (4M x 2N), per-wave 32x96, acc[2][6].
// Co-resident blocks stagger staging bursts (R11 occupancy showed 80KB LDS -> only 1
// block/CU; 40KB guarantees 2). 64-B rows: chunk swizzle c = g ^ ((row>>1)&3) (2-way
// max = free), inverse pre-applied to global src. Waves 0-3 issue 3 loads/tile, 4-7
// issue 2 -> split vmcnt(3)/(2). Q pre-scaled by QSCALE in epilogue.
__global__ __launch_bounds__(512) void k_gemm_qkv(const u16* __restrict__ A,
                                                  const u16* __restrict__ B,
                                                  u16* __restrict__ Qp,
                                                  u16* __restrict__ Kp,
                                                  u16* __restrict__ Vtp) {
    constexpr float QSCALE = 0.18033688f;  // SCALE * log2(e)
    __shared__ __align__(16) char smem[40960];  // 2 bufs x (A 8KB + B 12KB)
    const int tid = threadIdx.x;
    const int lane = tid & 63, wid = tid >> 6;
    const int r = lane & 15, g = lane >> 4;
    const int wm = wid >> 1, wn = wid & 1;
    const int lin = blockIdx.x;                    // 512 blocks; 64/XCD = 4 m-rows
    const int wg = (lin & 7) * 64 + (lin >> 3);
    const int m0 = (wg >> 4) * 128, n0 = (wg & 15) * 192;

    f32x4 acc[2][6] = {};

    // ds_read bases (buf0): row*64 + swizzled 16B chunk; + buf*20480
    const int cswz = (g ^ ((r >> 1) & 3)) << 4;
    int vA[2], vB[6];
#pragma unroll
    for (int m = 0; m < 2; ++m)
        vA[m] = (wm * 32 + m * 16 + r) * 64 + cswz;
#pragma unroll
    for (int j = 0; j < 6; ++j)
        vB[j] = 8192 + (wn * 96 + j * 16 + r) * 64 + cswz;
    const char* lds = (const char*)smem;

    // staging: thread covers 16B chunk (tid&3) of row (tid>>2); src chunk inverse-swz
    const int srow = tid >> 2;                                   // 0..127
    const int scol = ((tid & 3) ^ ((tid >> 3) & 3)) * 8;         // u16 units
    const u16* aS = A + (size_t)(m0 + srow) * 1024 + scol;
    const u16* bS = B + (size_t)(n0 + srow) * 1024 + scol;
    char* ldsT = (char*)smem + tid * 16;

    auto STAGE = [&](int buf, int t) {
        const u16* a = aS + t * 32;
        const u16* b = bS + t * 32;
        async16(ldsT + buf * 20480, a);                    // A rows 0..127
        async16(ldsT + buf * 20480 + 8192, b);             // B rows 0..127
        if (tid < 256)                                     // wave-uniform (waves 0-3)
            async16(ldsT + buf * 20480 + 16384, b + 131072);  // B rows 128..191
    };

    STAGE(0, 0);  // prologue

    for (int t = 0; t < 32; ++t) {
        const int buf = t & 1;
        if (t < 31) {
            STAGE(buf ^ 1, t + 1);
            if (wid < 4) asm volatile("s_waitcnt vmcnt(3)" ::: "memory");
            else         asm volatile("s_waitcnt vmcnt(2)" ::: "memory");
        } else {
            asm volatile("s_waitcnt vmcnt(0)" ::: "memory");
        }
        __builtin_amdgcn_s_barrier();
        asm volatile("" ::: "memory");

        bf16x8 a0 = *(const bf16x8*)(lds + buf * 20480 + vA[0]);
        bf16x8 a1 = *(const bf16x8*)(lds + buf * 20480 + vA[1]);
        __builtin_amdgcn_s_setprio(1);
#pragma unroll
        for (int j = 0; j < 6; ++j) {
            bf16x8 b = *(const bf16x8*)(lds + buf * 20480 + vB[j]);
            acc[0][j] = __builtin_amdgcn_mfma_f32_16x16x32_bf16(a0, b, acc[0][j], 0, 0, 0);
            acc[1][j] = __builtin_amdgcn_mfma_f32_16x16x32_bf16(a1, b, acc[1][j], 0, 0, 0);
        }
        __builtin_amdgcn_s_setprio(0);
        asm volatile("s_waitcnt lgkmcnt(0)" ::: "memory");  // reads done before overwrite
        __builtin_amdgcn_s_barrier();
        asm volatile("" ::: "memory");
    }

    // scatter epilogue, per 32-col pair (pairs 32-aligned; which constant per pair): h = r
#pragma unroll
    for (int jp = 0; jp < 3; ++jp) {
        const int f0 = n0 + wn * 96 + jp * 32;
        const int which = f0 >> 10;
        const int d0 = (f0 & 1023) >> 4;
        if (which == 0) {  // Q: pre-scale by QSCALE
#pragma unroll
            for (int m = 0; m < 2; ++m) {
#pragma unroll
                for (int reg = 0; reg < 4; ++reg) {
                    int tt = m0 + wm * 32 + m * 16 + g * 4 + reg;
                    int b = tt >> 11, t = tt & 2047;
                    *(uint32_t*)(Qp + (((size_t)(b * 16 + r) * 2048 + t) * 64 + d0))
                        = pack2(acc[m][2 * jp][reg] * QSCALE, acc[m][2 * jp + 1][reg] * QSCALE);
                }
            }
        } else if (which == 1) {  // K
#pragma unroll
            for (int m = 0; m < 2; ++m) {
#pragma unroll
                for (int reg = 0; reg < 4; ++reg) {
                    int tt = m0 + wm * 32 + m * 16 + g * 4 + reg;
                    int b = tt >> 11, t = tt & 2047;
                    *(uint32_t*)(Kp + (((size_t)(b * 16 + r) * 2048 + t) * 64 + d0))
                        = pack2(acc[m][2 * jp][reg], acc[m][2 * jp + 1][reg]);
                }
            }
        } else {  // V -> Vt
#pragma unroll
            for (int m = 0; m < 2; ++m) {
                int tt0 = m0 + wm * 32 + m * 16 + g * 4;
                int b = tt0 >> 11, t0 = tt0 & 2047;
#pragma unroll
                for (int dj = 0; dj < 2; ++dj) {
                    uint2 val;
                    val.x = pack2(acc[m][2 * jp + dj][0], acc[m][2 * jp + dj][1]);
                    val.y = pack2(acc[m][2 * jp + dj][2], acc[m][2 * jp + dj][3]);
                    *(uint2*)(Vtp + (((size_t)(b * 16 + r) * 64 + d0 + dj) * 2048 + t0)) = val;
                }
            }
        }
    }
}

// ============ out-proj GEMM: 128x128 tile, BK=64, 2-barrier/tile, f32 out ============
__global__ __launch_bounds__(512) void k_gemm_out(const u16* __restrict__ A,
                                                  const u16* __restrict__ B,
                                                  float* __restrict__ C) {
    __shared__ __align__(16) char smem[65536];
    const int tid = threadIdx.x;
    const int lane = tid & 63, wid = tid >> 6;
    const int r = lane & 15, g = lane >> 4;
    const int wm = wid >> 2, wn = wid & 3;
    const int lin = blockIdx.x;                    // 256 blocks
    const int wg = (lin & 7) * 32 + (lin >> 3);
    const int m0 = (wg >> 3) * 128, n0 = (wg & 7) * 128;

    f32x4 acc[4][2] = {};

    const int colswz = (g ^ (r & 7)) << 4;
    int vA[4], vB[2];
#pragma unroll
    for (int m = 0; m < 4; ++m) {
        int ii = wm * 64 + m * 16 + r;
        vA[m] = (ii >> 6) * 8192 + (ii & 63) * 128 + colswz;          // + buf*16384
    }
#pragma unroll
    for (int n = 0; n < 2; ++n) {
        int jj = wn * 32 + n * 16 + r;
        vB[n] = 32768 + (jj >> 6) * 8192 + (jj & 63) * 128 + colswz;  // + buf*16384
    }
    const char* lds = (const char*)smem;

    const int lr = tid >> 3;
    const int scol = (((tid & 7) * 16) ^ ((lr & 7) << 4)) >> 1;
    const u16* aS = A + (size_t)(m0 + lr) * 1024 + scol;
    const u16* bS = B + (size_t)(n0 + lr) * 1024 + scol;
    char* ldsT = (char*)smem + tid * 16;

    auto STAGE_ALL = [&](int buf, int t) {
        const u16* a = aS + t * 64;
        const u16* b = bS + t * 64;
        async16(ldsT + buf * 16384,          a);
        async16(ldsT + buf * 16384 + 8192,   a + 65536);
        async16(ldsT + 32768 + buf * 16384,        b);
        async16(ldsT + 32768 + buf * 16384 + 8192, b + 65536);
    };

    STAGE_ALL(0, 0);

    for (int t = 0; t < 16; ++t) {
        const int buf = t & 1;
        if (t < 15) {
            STAGE_ALL(buf ^ 1, t + 1);
            asm volatile("s_waitcnt vmcnt(4)" ::: "memory");
        } else {
            asm volatile("s_waitcnt vmcnt(0)" ::: "memory");
        }
        __builtin_amdgcn_s_barrier();
        asm volatile("" ::: "memory");

        bf16x8 a[4][2], b[2][2];
#pragma unroll
        for (int m = 0; m < 4; ++m) {
            int ad = buf * 16384 + vA[m];
            a[m][0] = *(const bf16x8*)(lds + ad);
            a[m][1] = *(const bf16x8*)(lds + (ad ^ 64));
        }
#pragma unroll
        for (int n = 0; n < 2; ++n) {
            int bd = buf * 16384 + vB[n];
            b[n][0] = *(const bf16x8*)(lds + bd);
            b[n][1] = *(const bf16x8*)(lds + (bd ^ 64));
        }
        __builtin_amdgcn_s_setprio(1);
#pragma unroll
        for (int m = 0; m < 4; ++m)
#pragma unroll
            for (int n = 0; n < 2; ++n) {
                acc[m][n] = __builtin_amdgcn_mfma_f32_16x16x32_bf16(a[m][0], b[n][0], acc[m][n], 0, 0, 0);
                acc[m][n] = __builtin_amdgcn_mfma_f32_16x16x32_bf16(a[m][1], b[n][1], acc[m][n], 0, 0, 0);
            }
        __builtin_amdgcn_s_setprio(0);
        asm volatile("s_waitcnt lgkmcnt(0)" ::: "memory");
        __builtin_amdgcn_s_barrier();
        asm volatile("" ::: "memory");
    }

#pragma unroll
    for (int m = 0; m < 4; ++m) {
#pragma unroll
        for (int reg = 0; reg < 4; ++reg) {
            size_t crow = (size_t)(m0 + wm * 64 + m * 16 + g * 4 + reg);
#pragma unroll
            for (int n = 0; n < 2; ++n)
                C[crow * 1024 + n0 + wn * 32 + n * 16 + r] = acc[m][n][reg];
        }
    }
}

// ---------------- flash attention: 8 warps x 32 q-rows, K prefetch-2 / V prefetch-1 ----
// Q pre-scaled -> P = exp2(S). Row-sum via MFMA(ones, P). K 4-buf (write (t+2)&3),
// V 4-buf (write (t+1)&3); safe under <=1-iter wave skew (disjoint mod-4 distances).
// vmcnt by queue simulation: steady 4; tail 4/4/3/1; 0 before final PV.
__global__ __launch_bounds__(512, 1) void k_attn(const u16* __restrict__ Qp,
                                                 const u16* __restrict__ Kp,
                                                 const u16* __restrict__ Vtp,
                                                 u16* __restrict__ O) {
    constexpr int T = 2048;
    // K0..K3 @ 0,8192,16384,24576 | V0..V3 @ 32768,40960,49152,57344
    __shared__ __align__(16) char smem[65536];

    const int tid = threadIdx.x;
    const int lane = tid & 63, wv = tid >> 6;
    const int l31 = lane & 31, hi = lane >> 5;

    const int lin = blockIdx.x;
    const int work = (lin & 7) * 32 + (lin >> 3);
    const int bh = work >> 3, qchunk = work & 7;
    const int q0 = qchunk * 256 + wv * 32;

    const u16* Qb = Qp + (size_t)bh * T * 64;
    const u16* Kb = Kp + (size_t)bh * T * 64;
    const u16* Vb = Vtp + (size_t)bh * 64 * T;

    const u16* qrow = Qb + (size_t)(q0 + l31) * 64 + hi * 8;
    bf16x8 qf[4];
#pragma unroll
    for (int kb = 0; kb < 4; ++kb) qf[kb] = *(const bf16x8*)(qrow + kb * 16);

    const char* ldsB = (const char*)smem;
    int off[4];
#pragma unroll
    for (int s = 0; s < 4; ++s)
        off[s] = l31 * 128 + ((((2 * s + hi) ^ (l31 & 7))) << 4);

    const int srow = tid >> 3;                                   // 0..63
    const int scol = (((tid & 7) * 16) ^ ((srow & 7) << 4)) >> 1;
    const u16* kSrc = Kb + srow * 64 + scol;
    const u16* vSrc = Vb + (size_t)srow * T + scol;
    char* ldsT = smem + tid * 16;

    u32x4 onesu; onesu.x = 0x3F803F80u; onesu.y = 0x3F803F80u;
    onesu.z = 0x3F803F80u; onesu.w = 0x3F803F80u;
    const bf16x8 ones8 = __builtin_bit_cast(bf16x8, onesu);

    f32x16 st[2], oa[2], ls;
    f32x16 z;
#pragma unroll
    for (int e = 0; e < 16; ++e) { z[e] = 0.f; oa[0][e] = 0.f; oa[1][e] = 0.f; ls[e] = 0.f; }
    bf16x8 pf[4] = {};

    // compute body for tile it: QK from KB, PV(it-1)+sum from VBprev, exp, pack
    auto body = [&](int KB, int VBprev, bool dopv) {
        __builtin_amdgcn_s_setprio(1);
        {
            bf16x8 k0 = *(const bf16x8*)(ldsB + off[0] + KB);
            bf16x8 k1 = *(const bf16x8*)(ldsB + off[0] + KB + 4096);
            st[0] = __builtin_amdgcn_mfma_f32_32x32x16_bf16(k0, qf[0], z, 0, 0, 0);
            st[1] = __builtin_amdgcn_mfma_f32_32x32x16_bf16(k1, qf[0], z, 0, 0, 0);
        }
#pragma unroll
        for (int kb = 1; kb < 4; ++kb) {
            bf16x8 k0 = *(const bf16x8*)(ldsB + off[kb] + KB);
            bf16x8 k1 = *(const bf16x8*)(ldsB + off[kb] + KB + 4096);
            st[0] = __builtin_amdgcn_mfma_f32_32x32x16_bf16(k0, qf[kb], st[0], 0, 0, 0);
            st[1] = __builtin_amdgcn_mfma_f32_32x32x16_bf16(k1, qf[kb], st[1], 0, 0, 0);
        }
        if (dopv) {
#pragma unroll
            for (int jk = 0; jk < 4; ++jk) {
                bf16x8 v0 = *(const bf16x8*)(ldsB + off[jk] + VBprev);
                bf16x8 v1 = *(const bf16x8*)(ldsB + off[jk] + VBprev + 4096);
                oa[0] = __builtin_amdgcn_mfma_f32_32x32x16_bf16(v0, pf[jk], oa[0], 0, 0, 0);
                oa[1] = __builtin_amdgcn_mfma_f32_32x32x16_bf16(v1, pf[jk], oa[1], 0, 0, 0);
                ls    = __builtin_amdgcn_mfma_f32_32x32x16_bf16(ones8, pf[jk], ls, 0, 0, 0);
            }
        }
        __builtin_amdgcn_s_setprio(0);

#pragma unroll
        for (int tt = 0; tt < 2; ++tt)
#pragma unroll
            for (int e = 0; e < 16; ++e)
                st[tt][e] = exp2r(st[tt][e]);

#pragma unroll
        for (int t2 = 0; t2 < 2; ++t2) {
            uint32_t c0 = cvtpk(st[t2][0], st[t2][1]);
            uint32_t c1 = cvtpk(st[t2][2], st[t2][3]);
            uint32_t c2 = cvtpk(st[t2][4], st[t2][5]);
            uint32_t c3 = cvtpk(st[t2][6], st[t2][7]);
            uint32_t c4 = cvtpk(st[t2][8], st[t2][9]);
            uint32_t c5 = cvtpk(st[t2][10], st[t2][11]);
            uint32_t c6 = cvtpk(st[t2][12], st[t2][13]);
            uint32_t c7 = cvtpk(st[t2][14], st[t2][15]);
            u32x2v s0 = __builtin_amdgcn_permlane32_swap(c0, c2, false, false);
            u32x2v s1 = __builtin_amdgcn_permlane32_swap(c1, c3, false, false);
            u32x2v s2 = __builtin_amdgcn_permlane32_swap(c4, c6, false, false);
            u32x2v s3 = __builtin_amdgcn_permlane32_swap(c5, c7, false, false);
            u32x4 f0; f0.x = s0[0]; f0.y = s1[0]; f0.z = s0[1]; f0.w = s1[1];
            u32x4 f1; f1.x = s2[0]; f1.y = s3[0]; f1.z = s2[1]; f1.w = s3[1];
            pf[2 * t2]     = __builtin_bit_cast(bf16x8, f0);
            pf[2 * t2 + 1] = __builtin_bit_cast(bf16x8, f1);
        }
        asm volatile("" ::: "memory");
    };

    // prologue: K0 -> Kbuf0, V0 -> Vbuf0, K1 -> Kbuf1  (queue: [K0, V0, K1])
    async16(ldsT, kSrc);
    async16(ldsT + 32768, vSrc);
    async16(ldsT + 8192, kSrc + 4096);

    // main loop: it = 0..27. stage K(it+2) -> (it+2)&3, V(it+1) -> (it+1)&3; vmcnt(4).
    for (int it4 = 0; it4 < 7; ++it4) {
#pragma unroll
        for (int sub = 0; sub < 4; ++sub) {
            const int it = it4 * 4 + sub;
            const int KB = sub * 8192;
            const int VBprev = 32768 + ((sub + 3) & 3) * 8192;
            async16(ldsT + ((sub + 2) & 3) * 8192, kSrc + (size_t)(it + 2) * 4096);
            async16(ldsT + 32768 + ((sub + 1) & 3) * 8192, vSrc + (it + 1) * 64);
            asm volatile("s_waitcnt vmcnt(4)" ::: "memory");
            __builtin_amdgcn_s_barrier();
            asm volatile("" ::: "memory");
            body(KB, VBprev, it != 0);
        }
    }

    // tail: it = 28..31 (peeled; vmcnt by queue simulation)
    async16(ldsT + 16384, kSrc + (size_t)30 * 4096);
    async16(ldsT + 32768 + 8192, vSrc + 29 * 64);
    asm volatile("s_waitcnt vmcnt(4)" ::: "memory");
    __builtin_amdgcn_s_barrier();
    asm volatile("" ::: "memory");
    body(0, 32768 + 24576, true);
    async16(ldsT + 24576, kSrc + (size_t)31 * 4096);
    async16(ldsT + 32768 + 16384, vSrc + 30 * 64);
    asm volatile("s_waitcnt vmcnt(4)" ::: "memory");
    __builtin_amdgcn_s_barrier();
    asm volatile("" ::: "memory");
    body(8192, 32768, true);
    async16(ldsT + 32768 + 24576, vSrc + 31 * 64);
    asm volatile("s_waitcnt vmcnt(3)" ::: "memory");
    __builtin_amdgcn_s_barrier();
    asm volatile("" ::: "memory");
    body(16384, 32768 + 8192, true);
    asm volatile("s_waitcnt vmcnt(1)" ::: "memory");
    __builtin_amdgcn_s_barrier();
    asm volatile("" ::: "memory");
    body(24576, 32768 + 16384, true);

    // final PV(31): V31 in Vbuf3
    asm volatile("s_waitcnt vmcnt(0)" ::: "memory");
    __builtin_amdgcn_s_barrier();
    asm volatile("" ::: "memory");
#pragma unroll
    for (int jk = 0; jk < 4; ++jk) {
        bf16x8 v0 = *(const bf16x8*)(ldsB + off[jk] + 57344);
        bf16x8 v1 = *(const bf16x8*)(ldsB + off[jk] + 57344 + 4096);
        oa[0] = __builtin_amdgcn_mfma_f32_32x32x16_bf16(v0, pf[jk], oa[0], 0, 0, 0);
        oa[1] = __builtin_amdgcn_mfma_f32_32x32x16_bf16(v1, pf[jk], oa[1], 0, 0, 0);
        ls    = __builtin_amdgcn_mfma_f32_32x32x16_bf16(ones8, pf[jk], ls, 0, 0, 0);
    }

    // epilogue: ls[0] = full row sum for q-col l31
    float linv = 1.0f / ls[0];
    const int b = bh >> 4, h = bh & 15;
    u16* obase = O + ((size_t)b * T + q0 + l31) * 1024 + h * 64 + 4 * hi;
#pragma unroll
    for (int q = 0; q < 8; ++q) {
        int dbase = ((2 * q) & 3) + 8 * (q >> 1);
        *(uint32_t*)(obase + dbase)      = pack2(oa[0][2 * q] * linv, oa[0][2 * q + 1] * linv);
        *(uint32_t*)(obase + 32 + dbase) = pack2(oa[1][2 * q] * linv, oa[1][2 * q + 1] * linv);
    }
}

extern "C" void kernel_launch(void* const* d_in, const int* in_sizes, int n_in,
                              void* d_out, int out_size, void* d_ws, size_t ws_size,
                              hipStream_t stream) {
    const float* x    = (const float*)d_in[0];  // [2,2048,1024]
    const float* wqkv = (const float*)d_in[1];  // [3072,1024]
    const float* wout = (const float*)d_in[2];  // [1024,1024]
    float* out = (float*)d_out;
    char* ws = (char*)d_ws;

    u16* xb   = (u16*)(ws);                    //  8,388,608 B
    u16* wqb  = (u16*)(ws + 8388608);          //  6,291,456
    u16* wob  = (u16*)(ws + 14680064);         //  2,097,152
    u16* Qp   = (u16*)(ws + 41943040);         //  8,388,608
    u16* Kp   = (u16*)(ws + 50331648);         //  8,388,608
    u16* Vtp  = (u16*)(ws + 58720256);         //  8,388,608
    u16* Ob   = (u16*)(ws + 67108864);         //  8,388,608

    k_cvt3<<<4096, 256, 0, stream>>>(x, wqkv, wout, xb, wqb, wob);
    k_gemm_qkv<<<dim3(512), 512, 0, stream>>>(xb, wqb, Qp, Kp, Vtp);
    k_attn<<<dim3(256), dim3(512), 0, stream>>>(Qp, Kp, Vtp, Ob);
    k_gemm_out<<<dim3(256), 512, 0, stream>>>(Ob, wob, out);
}

// Round 13
// 110.773 us; speedup vs baseline: 1.0438x; 1.0438x over previous
//
#include <hip/hip_runtime.h>
#include <hip/hip_bf16.h>
#include <stdint.h>

// MSA: x[2,2048,1024] fp32, w_qkv[3072,1024], w_out[1024,1024] -> out[2,2048,1024] fp32
// Internal bf16 MFMA. B=2 T=2048 E=1024 H=16 D=64, SCALE=1/8.
// Q is pre-scaled by ALPHA = SCALE*log2(e) in the QKV epilogue; attn uses exp2 directly.

using u16 = uint16_t;
typedef __bf16 bf16x8 __attribute__((ext_vector_type(8)));
typedef float f32x4 __attribute__((ext_vector_type(4)));
typedef float f32x16 __attribute__((ext_vector_type(16)));
typedef unsigned short ushort8 __attribute__((ext_vector_type(8)));
typedef uint32_t u32x4 __attribute__((ext_vector_type(4)));
typedef unsigned int u32x2v __attribute__((ext_vector_type(2)));

#define DEV __device__ __forceinline__

typedef __attribute__((address_space(1))) void as1_void;
typedef __attribute__((address_space(3))) void as3_void;

DEV void async16(void* lds_uniform, const void* gsrc) {
    __builtin_amdgcn_global_load_lds((as1_void*)(gsrc), (as3_void*)(lds_uniform), 16, 0, 0);
}

DEV uint16_t f2bf(float x) {  // RNE fp32->bf16 (finite inputs)
    uint32_t u = __builtin_bit_cast(uint32_t, x);
    u += 0x7fffu + ((u >> 16) & 1u);
    return (uint16_t)(u >> 16);
}

DEV uint32_t pack2(float a, float b) {
    return (uint32_t)f2bf(a) | ((uint32_t)f2bf(b) << 16);
}

DEV uint32_t cvtpk(float lo, float hi) {  // v_cvt_pk_bf16_f32
    uint32_t r;
    asm("v_cvt_pk_bf16_f32 %0, %1, %2" : "=v"(r) : "v"(lo), "v"(hi));
    return r;
}

DEV float exp2r(float x) { return __builtin_amdgcn_exp2f(x); }  // raw v_exp_f32

// ---------------- fused fp32 -> bf16 cast for x, w_qkv, w_out ----------------
__global__ __launch_bounds__(256) void k_cvt3(const float* __restrict__ x,
                                              const float* __restrict__ wq,
                                              const float* __restrict__ wo,
                                              u16* __restrict__ xb,
                                              u16* __restrict__ wqb,
                                              u16* __restrict__ wob) {
    int i = blockIdx.x * 256 + threadIdx.x;  // 0 .. 1048575 (x8 elems)
    const float* in;
    u16* out;
    int j;
    if (i < 524288)       { in = x;  out = xb;  j = i; }
    else if (i < 917504)  { in = wq; out = wqb; j = i - 524288; }
    else                  { in = wo; out = wob; j = i - 917504; }
    const float4* p = (const float4*)in;
    float4 a = p[2 * (size_t)j], b = p[2 * (size_t)j + 1];
    ushort8 o;
    o[0] = f2bf(a.x); o[1] = f2bf(a.y); o[2] = f2bf(a.z); o[3] = f2bf(a.w);
    o[4] = f2bf(b.x); o[5] = f2bf(b.y); o[6] = f2bf(b.z); o[7] = f2bf(b.w);
    *(ushort8*)(out + 8 * (size_t)j) = o;
}

// ================= QKV GEMM: 128x192 tile, BK=64, 2-barrier/tile =====================
// (R11 structure — measured best: 49.2us, MfmaUtil ~20%, conflicts 0.)
// C[4096,3072] = xb * wqb^T. 512 blocks, LDS 80KB. 8 waves (4M x 2N), per-wave 32x96,
// acc[2][6]. XOR swizzle both-sides. Q pre-scaled by QSCALE in epilogue.
__global__ __launch_bounds__(512) void k_gemm_qkv(const u16* __restrict__ A,
                                                  const u16* __restrict__ B,
                                                  u16* __restrict__ Qp,
                                                  u16* __restrict__ Kp,
                                                  u16* __restrict__ Vtp) {
    constexpr float QSCALE = 0.18033688f;  // SCALE * log2(e)
    __shared__ __align__(16) char smem[81920];
    const int tid = threadIdx.x;
    const int lane = tid & 63, wid = tid >> 6;
    const int r = lane & 15, g = lane >> 4;
    const int wm = wid >> 1, wn = wid & 1;
    const int lin = blockIdx.x;                    // 512 blocks; 64/XCD = 4 m-rows
    const int wg = (lin & 7) * 64 + (lin >> 3);
    const int m0 = (wg >> 4) * 128, n0 = (wg & 15) * 192;

    f32x4 acc[2][6] = {};

    const int colswz = (g ^ (r & 7)) << 4;
    int vA[2], vB[6];
#pragma unroll
    for (int m = 0; m < 2; ++m)
        vA[m] = (wm * 32 + m * 16 + r) * 128 + colswz;               // + buf*16384; kk1 = ^64
#pragma unroll
    for (int j = 0; j < 6; ++j)
        vB[j] = 32768 + (wn * 96 + j * 16 + r) * 128 + colswz;       // + buf*24576
    const char* lds = (const char*)smem;

    const int lr = tid >> 3;                                    // 0..63
    const int scol = (((tid & 7) * 16) ^ ((lr & 7) << 4)) >> 1; // u16 units
    const u16* aS = A + (size_t)(m0 + lr) * 1024 + scol;
    const u16* bS = B + (size_t)(n0 + lr) * 1024 + scol;
    char* ldsT = (char*)smem + tid * 16;

    auto STAGE_ALL = [&](int buf, int t) {
        const u16* a = aS + t * 64;
        const u16* b = bS + t * 64;
        char* dA = ldsT + buf * 16384;
        char* dB = ldsT + 32768 + buf * 24576;
        async16(dA,          a);             // A rows   0..63
        async16(dA + 8192,   a + 65536);     // A rows  64..127
        async16(dB,          b);             // B rows   0..63
        async16(dB + 8192,   b + 65536);     // B rows  64..127
        async16(dB + 16384,  b + 131072);    // B rows 128..191
    };

    STAGE_ALL(0, 0);  // prologue

    for (int t = 0; t < 16; ++t) {
        const int buf = t & 1;
        if (t < 15) {
            STAGE_ALL(buf ^ 1, t + 1);
            asm volatile("s_waitcnt vmcnt(5)" ::: "memory");  // tile t landed; t+1 in flight
        } else {
            asm volatile("s_waitcnt vmcnt(0)" ::: "memory");
        }
        __builtin_amdgcn_s_barrier();
        asm volatile("" ::: "memory");

        bf16x8 a[2][2];
#pragma unroll
        for (int m = 0; m < 2; ++m) {
            int ad = buf * 16384 + vA[m];
            a[m][0] = *(const bf16x8*)(lds + ad);
            a[m][1] = *(const bf16x8*)(lds + (ad ^ 64));
        }
        __builtin_amdgcn_s_setprio(1);
#pragma unroll
        for (int j = 0; j < 6; ++j) {
            int bd = buf * 24576 + vB[j];
            bf16x8 b0 = *(const bf16x8*)(lds + bd);
            bf16x8 b1 = *(const bf16x8*)(lds + (bd ^ 64));
#pragma unroll
            for (int m = 0; m < 2; ++m) {
                acc[m][j] = __builtin_amdgcn_mfma_f32_16x16x32_bf16(a[m][0], b0, acc[m][j], 0, 0, 0);
                acc[m][j] = __builtin_amdgcn_mfma_f32_16x16x32_bf16(a[m][1], b1, acc[m][j], 0, 0, 0);
            }
        }
        __builtin_amdgcn_s_setprio(0);
        asm volatile("s_waitcnt lgkmcnt(0)" ::: "memory");  // reads done before next overwrite
        __builtin_amdgcn_s_barrier();
        asm volatile("" ::: "memory");
    }

    // scatter epilogue, per 32-col pair (pairs 32-aligned; which constant per pair): h = r
#pragma unroll
    for (int jp = 0; jp < 3; ++jp) {
        const int f0 = n0 + wn * 96 + jp * 32;
        const int which = f0 >> 10;
        const int d0 = (f0 & 1023) >> 4;
        if (which == 0) {  // Q: pre-scale by QSCALE
#pragma unroll
            for (int m = 0; m < 2; ++m) {
#pragma unroll
                for (int reg = 0; reg < 4; ++reg) {
                    int tt = m0 + wm * 32 + m * 16 + g * 4 + reg;
                    int b = tt >> 11, t = tt & 2047;
                    *(uint32_t*)(Qp + (((size_t)(b * 16 + r) * 2048 + t) * 64 + d0))
                        = pack2(acc[m][2 * jp][reg] * QSCALE, acc[m][2 * jp + 1][reg] * QSCALE);
                }
            }
        } else if (which == 1) {  // K
#pragma unroll
            for (int m = 0; m < 2; ++m) {
#pragma unroll
                for (int reg = 0; reg < 4; ++reg) {
                    int tt = m0 + wm * 32 + m * 16 + g * 4 + reg;
                    int b = tt >> 11, t = tt & 2047;
                    *(uint32_t*)(Kp + (((size_t)(b * 16 + r) * 2048 + t) * 64 + d0))
                        = pack2(acc[m][2 * jp][reg], acc[m][2 * jp + 1][reg]);
                }
            }
        } else {  // V -> Vt
#pragma unroll
            for (int m = 0; m < 2; ++m) {
                int tt0 = m0 + wm * 32 + m * 16 + g * 4;
                int b = tt0 >> 11, t0 = tt0 & 2047;
#pragma unroll
                for (int dj = 0; dj < 2; ++dj) {
                    uint2 val;
                    val.x = pack2(acc[m][2 * jp + dj][0], acc[m][2 * jp + dj][1]);
                    val.y = pack2(acc[m][2 * jp + dj][2], acc[m][2 * jp + dj][3]);
                    *(uint2*)(Vtp + (((size_t)(b * 16 + r) * 64 + d0 + dj) * 2048 + t0)) = val;
                }
            }
        }
    }
}

// ============ out-proj GEMM: 128x128 tile, BK=64, 2-barrier/tile, f32 out ============
__global__ __launch_bounds__(512) void k_gemm_out(const u16* __restrict__ A,
                                                  const u16* __restrict__ B,
                                                  float* __restrict__ C) {
    __shared__ __align__(16) char smem[65536];
    const int tid = threadIdx.x;
    const int lane = tid & 63, wid = tid >> 6;
    const int r = lane & 15, g = lane >> 4;
    const int wm = wid >> 2, wn = wid & 3;
    const int lin = blockIdx.x;                    // 256 blocks
    const int wg = (lin & 7) * 32 + (lin >> 3);
    const int m0 = (wg >> 3) * 128, n0 = (wg & 7) * 128;

    f32x4 acc[4][2] = {};

    const int colswz = (g ^ (r & 7)) << 4;
    int vA[4], vB[2];
#pragma unroll
    for (int m = 0; m < 4; ++m) {
        int ii = wm * 64 + m * 16 + r;
        vA[m] = (ii >> 6) * 8192 + (ii & 63) * 128 + colswz;          // + buf*16384
    }
#pragma unroll
    for (int n = 0; n < 2; ++n) {
        int jj = wn * 32 + n * 16 + r;
        vB[n] = 32768 + (jj >> 6) * 8192 + (jj & 63) * 128 + colswz;  // + buf*16384
    }
    const char* lds = (const char*)smem;

    const int lr = tid >> 3;
    const int scol = (((tid & 7) * 16) ^ ((lr & 7) << 4)) >> 1;
    const u16* aS = A + (size_t)(m0 + lr) * 1024 + scol;
    const u16* bS = B + (size_t)(n0 + lr) * 1024 + scol;
    char* ldsT = (char*)smem + tid * 16;

    auto STAGE_ALL = [&](int buf, int t) {
        const u16* a = aS + t * 64;
        const u16* b = bS + t * 64;
        async16(ldsT + buf * 16384,          a);
        async16(ldsT + buf * 16384 + 8192,   a + 65536);
        async16(ldsT + 32768 + buf * 16384,        b);
        async16(ldsT + 32768 + buf * 16384 + 8192, b + 65536);
    };

    STAGE_ALL(0, 0);

    for (int t = 0; t < 16; ++t) {
        const int buf = t & 1;
        if (t < 15) {
            STAGE_ALL(buf ^ 1, t + 1);
            asm volatile("s_waitcnt vmcnt(4)" ::: "memory");
        } else {
            asm volatile("s_waitcnt vmcnt(0)" ::: "memory");
        }
        __builtin_amdgcn_s_barrier();
        asm volatile("" ::: "memory");

        bf16x8 a[4][2], b[2][2];
#pragma unroll
        for (int m = 0; m < 4; ++m) {
            int ad = buf * 16384 + vA[m];
            a[m][0] = *(const bf16x8*)(lds + ad);
            a[m][1] = *(const bf16x8*)(lds + (ad ^ 64));
        }
#pragma unroll
        for (int n = 0; n < 2; ++n) {
            int bd = buf * 16384 + vB[n];
            b[n][0] = *(const bf16x8*)(lds + bd);
            b[n][1] = *(const bf16x8*)(lds + (bd ^ 64));
        }
        __builtin_amdgcn_s_setprio(1);
#pragma unroll
        for (int m = 0; m < 4; ++m)
#pragma unroll
            for (int n = 0; n < 2; ++n) {
                acc[m][n] = __builtin_amdgcn_mfma_f32_16x16x32_bf16(a[m][0], b[n][0], acc[m][n], 0, 0, 0);
                acc[m][n] = __builtin_amdgcn_mfma_f32_16x16x32_bf16(a[m][1], b[n][1], acc[m][n], 0, 0, 0);
            }
        __builtin_amdgcn_s_setprio(0);
        asm volatile("s_waitcnt lgkmcnt(0)" ::: "memory");
        __builtin_amdgcn_s_barrier();
        asm volatile("" ::: "memory");
    }

#pragma unroll
    for (int m = 0; m < 4; ++m) {
#pragma unroll
        for (int reg = 0; reg < 4; ++reg) {
            size_t crow = (size_t)(m0 + wm * 64 + m * 16 + g * 4 + reg);
#pragma unroll
            for (int n = 0; n < 2; ++n)
                C[crow * 1024 + n0 + wn * 32 + n * 16 + r] = acc[m][n][reg];
        }
    }
}

// ---------------- flash attention: 8 warps x 32 q-rows, K prefetch-2 / V prefetch-1 ----
// Q pre-scaled -> P = exp2(S). Row-sum via MFMA(ones, P). K 4-buf (write (t+2)&3),
// V 4-buf (write (t+1)&3); safe under <=1-iter wave skew (disjoint mod-4 distances).
// vmcnt by queue simulation: steady 4; tail 4/4/3/1; 0 before final PV.
__global__ __launch_bounds__(512, 1) void k_attn(const u16* __restrict__ Qp,
                                                 const u16* __restrict__ Kp,
                                                 const u16* __restrict__ Vtp,
                                                 u16* __restrict__ O) {
    constexpr int T = 2048;
    // K0..K3 @ 0,8192,16384,24576 | V0..V3 @ 32768,40960,49152,57344
    __shared__ __align__(16) char smem[65536];

    const int tid = threadIdx.x;
    const int lane = tid & 63, wv = tid >> 6;
    const int l31 = lane & 31, hi = lane >> 5;

    const int lin = blockIdx.x;
    const int work = (lin & 7) * 32 + (lin >> 3);
    const int bh = work >> 3, qchunk = work & 7;
    const int q0 = qchunk * 256 + wv * 32;

    const u16* Qb = Qp + (size_t)bh * T * 64;
    const u16* Kb = Kp + (size_t)bh * T * 64;
    const u16* Vb = Vtp + (size_t)bh * 64 * T;

    const u16* qrow = Qb + (size_t)(q0 + l31) * 64 + hi * 8;
    bf16x8 qf[4];
#pragma unroll
    for (int kb = 0; kb < 4; ++kb) qf[kb] = *(const bf16x8*)(qrow + kb * 16);

    const char* ldsB = (const char*)smem;
    int off[4];
#pragma unroll
    for (int s = 0; s < 4; ++s)
        off[s] = l31 * 128 + ((((2 * s + hi) ^ (l31 & 7))) << 4);

    const int srow = tid >> 3;                                   // 0..63
    const int scol = (((tid & 7) * 16) ^ ((srow & 7) << 4)) >> 1;
    const u16* kSrc = Kb + srow * 64 + scol;
    const u16* vSrc = Vb + (size_t)srow * T + scol;
    char* ldsT = smem + tid * 16;

    u32x4 onesu; onesu.x = 0x3F803F80u; onesu.y = 0x3F803F80u;
    onesu.z = 0x3F803F80u; onesu.w = 0x3F803F80u;
    const bf16x8 ones8 = __builtin_bit_cast(bf16x8, onesu);

    f32x16 st[2], oa[2], ls;
    f32x16 z;
#pragma unroll
    for (int e = 0; e < 16; ++e) { z[e] = 0.f; oa[0][e] = 0.f; oa[1][e] = 0.f; ls[e] = 0.f; }
    bf16x8 pf[4] = {};

    // compute body for tile it: QK from KB, PV(it-1)+sum from VBprev, exp, pack
    auto body = [&](int KB, int VBprev, bool dopv) {
        __builtin_amdgcn_s_setprio(1);
        {
            bf16x8 k0 = *(const bf16x8*)(ldsB + off[0] + KB);
            bf16x8 k1 = *(const bf16x8*)(ldsB + off[0] + KB + 4096);
            st[0] = __builtin_amdgcn_mfma_f32_32x32x16_bf16(k0, qf[0], z, 0, 0, 0);
            st[1] = __builtin_amdgcn_mfma_f32_32x32x16_bf16(k1, qf[0], z, 0, 0, 0);
        }
#pragma unroll
        for (int kb = 1; kb < 4; ++kb) {
            bf16x8 k0 = *(const bf16x8*)(ldsB + off[kb] + KB);
            bf16x8 k1 = *(const bf16x8*)(ldsB + off[kb] + KB + 4096);
            st[0] = __builtin_amdgcn_mfma_f32_32x32x16_bf16(k0, qf[kb], st[0], 0, 0, 0);
            st[1] = __builtin_amdgcn_mfma_f32_32x32x16_bf16(k1, qf[kb], st[1], 0, 0, 0);
        }
        if (dopv) {
#pragma unroll
            for (int jk = 0; jk < 4; ++jk) {
                bf16x8 v0 = *(const bf16x8*)(ldsB + off[jk] + VBprev);
                bf16x8 v1 = *(const bf16x8*)(ldsB + off[jk] + VBprev + 4096);
                oa[0] = __builtin_amdgcn_mfma_f32_32x32x16_bf16(v0, pf[jk], oa[0], 0, 0, 0);
                oa[1] = __builtin_amdgcn_mfma_f32_32x32x16_bf16(v1, pf[jk], oa[1], 0, 0, 0);
                ls    = __builtin_amdgcn_mfma_f32_32x32x16_bf16(ones8, pf[jk], ls, 0, 0, 0);
            }
        }
        __builtin_amdgcn_s_setprio(0);

#pragma unroll
        for (int tt = 0; tt < 2; ++tt)
#pragma unroll
            for (int e = 0; e < 16; ++e)
                st[tt][e] = exp2r(st[tt][e]);

#pragma unroll
        for (int t2 = 0; t2 < 2; ++t2) {
            uint32_t c0 = cvtpk(st[t2][0], st[t2][1]);
            uint32_t c1 = cvtpk(st[t2][2], st[t2][3]);
            uint32_t c2 = cvtpk(st[t2][4], st[t2][5]);
            uint32_t c3 = cvtpk(st[t2][6], st[t2][7]);
            uint32_t c4 = cvtpk(st[t2][8], st[t2][9]);
            uint32_t c5 = cvtpk(st[t2][10], st[t2][11]);
            uint32_t c6 = cvtpk(st[t2][12], st[t2][13]);
            uint32_t c7 = cvtpk(st[t2][14], st[t2][15]);
            u32x2v s0 = __builtin_amdgcn_permlane32_swap(c0, c2, false, false);
            u32x2v s1 = __builtin_amdgcn_permlane32_swap(c1, c3, false, false);
            u32x2v s2 = __builtin_amdgcn_permlane32_swap(c4, c6, false, false);
            u32x2v s3 = __builtin_amdgcn_permlane32_swap(c5, c7, false, false);
            u32x4 f0; f0.x = s0[0]; f0.y = s1[0]; f0.z = s0[1]; f0.w = s1[1];
            u32x4 f1; f1.x = s2[0]; f1.y = s3[0]; f1.z = s2[1]; f1.w = s3[1];
            pf[2 * t2]     = __builtin_bit_cast(bf16x8, f0);
            pf[2 * t2 + 1] = __builtin_bit_cast(bf16x8, f1);
        }
        asm volatile("" ::: "memory");
    };

    // prologue: K0 -> Kbuf0, V0 -> Vbuf0, K1 -> Kbuf1  (queue: [K0, V0, K1])
    async16(ldsT, kSrc);
    async16(ldsT + 32768, vSrc);
    async16(ldsT + 8192, kSrc + 4096);

    // main loop: it = 0..27. stage K(it+2) -> (it+2)&3, V(it+1) -> (it+1)&3; vmcnt(4).
    for (int it4 = 0; it4 < 7; ++it4) {
#pragma unroll
        for (int sub = 0; sub < 4; ++sub) {
            const int it = it4 * 4 + sub;
            const int KB = sub * 8192;
            const int VBprev = 32768 + ((sub + 3) & 3) * 8192;
            async16(ldsT + ((sub + 2) & 3) * 8192, kSrc + (size_t)(it + 2) * 4096);
            async16(ldsT + 32768 + ((sub + 1) & 3) * 8192, vSrc + (it + 1) * 64);
            asm volatile("s_waitcnt vmcnt(4)" ::: "memory");
            __builtin_amdgcn_s_barrier();
            asm volatile("" ::: "memory");
            body(KB, VBprev, it != 0);
        }
    }

    // tail: it = 28..31 (peeled; vmcnt by queue simulation)
    async16(ldsT + 16384, kSrc + (size_t)30 * 4096);
    async16(ldsT + 32768 + 8192, vSrc + 29 * 64);
    asm volatile("s_waitcnt vmcnt(4)" ::: "memory");
    __builtin_amdgcn_s_barrier();
    asm volatile("" ::: "memory");
    body(0, 32768 + 24576, true);
    async16(ldsT + 24576, kSrc + (size_t)31 * 4096);
    async16(ldsT + 32768 + 16384, vSrc + 30 * 64);
    asm volatile("s_waitcnt vmcnt(4)" ::: "memory");
    __builtin_amdgcn_s_barrier();
    asm volatile("" ::: "memory");
    body(8192, 32768, true);
    async16(ldsT + 32768 + 24576, vSrc + 31 * 64);
    asm volatile("s_waitcnt vmcnt(3)" ::: "memory");
    __builtin_amdgcn_s_barrier();
    asm volatile("" ::: "memory");
    body(16384, 32768 + 8192, true);
    asm volatile("s_waitcnt vmcnt(1)" ::: "memory");
    __builtin_amdgcn_s_barrier();
    asm volatile("" ::: "memory");
    body(24576, 32768 + 16384, true);

    // final PV(31): V31 in Vbuf3
    asm volatile("s_waitcnt vmcnt(0)" ::: "memory");
    __builtin_amdgcn_s_barrier();
    asm volatile("" ::: "memory");
#pragma unroll
    for (int jk = 0; jk < 4; ++jk) {
        bf16x8 v0 = *(const bf16x8*)(ldsB + off[jk] + 57344);
        bf16x8 v1 = *(const bf16x8*)(ldsB + off[jk] + 57344 + 4096);
        oa[0] = __builtin_amdgcn_mfma_f32_32x32x16_bf16(v0, pf[jk], oa[0], 0, 0, 0);
        oa[1] = __builtin_amdgcn_mfma_f32_32x32x16_bf16(v1, pf[jk], oa[1], 0, 0, 0);
        ls    = __builtin_amdgcn_mfma_f32_32x32x16_bf16(ones8, pf[jk], ls, 0, 0, 0);
    }

    // epilogue: ls[0] = full row sum for q-col l31
    float linv = 1.0f / ls[0];
    const int b = bh >> 4, h = bh & 15;
    u16* obase = O + ((size_t)b * T + q0 + l31) * 1024 + h * 64 + 4 * hi;
#pragma unroll
    for (int q = 0; q < 8; ++q) {
        int dbase = ((2 * q) & 3) + 8 * (q >> 1);
        *(uint32_t*)(obase + dbase)      = pack2(oa[0][2 * q] * linv, oa[0][2 * q + 1] * linv);
        *(uint32_t*)(obase + 32 + dbase) = pack2(oa[1][2 * q] * linv, oa[1][2 * q + 1] * linv);
    }
}

extern "C" void kernel_launch(void* const* d_in, const int* in_sizes, int n_in,
                              void* d_out, int out_size, void* d_ws, size_t ws_size,
                              hipStream_t stream) {
    const float* x    = (const float*)d_in[0];  // [2,2048,1024]
    const float* wqkv = (const float*)d_in[1];  // [3072,1024]
    const float* wout = (const float*)d_in[2];  // [1024,1024]
    float* out = (float*)d_out;
    char* ws = (char*)d_ws;

    u16* xb   = (u16*)(ws);                    //  8,388,608 B
    u16* wqb  = (u16*)(ws + 8388608);          //  6,291,456
    u16* wob  = (u16*)(ws + 14680064);         //  2,097,152
    u16* Qp   = (u16*)(ws + 41943040);         //  8,388,608
    u16* Kp   = (u16*)(ws + 50331648);         //  8,388,608
    u16* Vtp  = (u16*)(ws + 58720256);         //  8,388,608
    u16* Ob   = (u16*)(ws + 67108864);         //  8,388,608

    k_cvt3<<<4096, 256, 0, stream>>>(x, wqkv, wout, xb, wqb, wob);
    k_gemm_qkv<<<dim3(512), 512, 0, stream>>>(xb, wqb, Qp, Kp, Vtp);
    k_attn<<<dim3(256), dim3(512), 0, stream>>>(Qp, Kp, Vtp, Ob);
    k_gemm_out<<<dim3(256), 512, 0, stream>>>(Ob, wob, out);
}

// Round 14
// 104.170 us; speedup vs baseline: 1.1099x; 1.0634x over previous
//
#include <hip/hip_runtime.h>
#include <hip/hip_bf16.h>
#include <stdint.h>

// MSA: x[2,2048,1024] fp32, w_qkv[3072,1024], w_out[1024,1024] -> out[2,2048,1024] fp32
// Internal bf16 MFMA. B=2 T=2048 E=1024 H=16 D=64, SCALE=1/8.
// Q is pre-scaled by ALPHA = SCALE*log2(e) in the QKV epilogue; attn uses exp2 directly.

using u16 = uint16_t;
typedef __bf16 bf16x8 __attribute__((ext_vector_type(8)));
typedef float f32x4 __attribute__((ext_vector_type(4)));
typedef float f32x16 __attribute__((ext_vector_type(16)));
typedef unsigned short ushort8 __attribute__((ext_vector_type(8)));
typedef uint32_t u32x4 __attribute__((ext_vector_type(4)));
typedef unsigned int u32x2v __attribute__((ext_vector_type(2)));

#define DEV __device__ __forceinline__

typedef __attribute__((address_space(1))) void as1_void;
typedef __attribute__((address_space(3))) void as3_void;

DEV void async16(void* lds_uniform, const void* gsrc) {
    __builtin_amdgcn_global_load_lds((as1_void*)(gsrc), (as3_void*)(lds_uniform), 16, 0, 0);
}

DEV uint16_t f2bf(float x) {  // RNE fp32->bf16 (finite inputs)
    uint32_t u = __builtin_bit_cast(uint32_t, x);
    u += 0x7fffu + ((u >> 16) & 1u);
    return (uint16_t)(u >> 16);
}

DEV uint32_t pack2(float a, float b) {
    return (uint32_t)f2bf(a) | ((uint32_t)f2bf(b) << 16);
}

DEV uint32_t cvtpk(float lo, float hi) {  // v_cvt_pk_bf16_f32
    uint32_t r;
    asm("v_cvt_pk_bf16_f32 %0, %1, %2" : "=v"(r) : "v"(lo), "v"(hi));
    return r;
}

DEV float exp2r(float x) { return __builtin_amdgcn_exp2f(x); }  // raw v_exp_f32

// ---------------- fused fp32 -> bf16 cast for x, w_qkv, w_out ----------------
__global__ __launch_bounds__(256) void k_cvt3(const float* __restrict__ x,
                                              const float* __restrict__ wq,
                                              const float* __restrict__ wo,
                                              u16* __restrict__ xb,
                                              u16* __restrict__ wqb,
                                              u16* __restrict__ wob) {
    int i = blockIdx.x * 256 + threadIdx.x;  // 0 .. 1048575 (x8 elems)
    const float* in;
    u16* out;
    int j;
    if (i < 524288)       { in = x;  out = xb;  j = i; }
    else if (i < 917504)  { in = wq; out = wqb; j = i - 524288; }
    else                  { in = wo; out = wob; j = i - 917504; }
    const float4* p = (const float4*)in;
    float4 a = p[2 * (size_t)j], b = p[2 * (size_t)j + 1];
    ushort8 o;
    o[0] = f2bf(a.x); o[1] = f2bf(a.y); o[2] = f2bf(a.z); o[3] = f2bf(a.w);
    o[4] = f2bf(b.x); o[5] = f2bf(b.y); o[6] = f2bf(b.z); o[7] = f2bf(b.w);
    *(ushort8*)(out + 8 * (size_t)j) = o;
}

// ================= QKV GEMM: 128x192 tile, BK=64, 2-barrier/tile =====================
// (R11 structure.) C[4096,3072] = xb * wqb^T. 512 blocks, LDS 80KB. 8 waves (4M x 2N),
// per-wave 32x96, acc[2][6]. XOR swizzle both-sides. Q pre-scaled by QSCALE.
// Epilogue: Q/K d-runs merged into aligned uint2+u32 (cuts L2 write sector-touches ~3x).
__global__ __launch_bounds__(512) void k_gemm_qkv(const u16* __restrict__ A,
                                                  const u16* __restrict__ B,
                                                  u16* __restrict__ Qp,
                                                  u16* __restrict__ Kp,
                                                  u16* __restrict__ Vtp) {
    constexpr float QSCALE = 0.18033688f;  // SCALE * log2(e)
    __shared__ __align__(16) char smem[81920];
    const int tid = threadIdx.x;
    const int lane = tid & 63, wid = tid >> 6;
    const int r = lane & 15, g = lane >> 4;
    const int wm = wid >> 1, wn = wid & 1;
    const int lin = blockIdx.x;                    // 512 blocks; 64/XCD = 4 m-rows
    const int wg = (lin & 7) * 64 + (lin >> 3);
    const int m0 = (wg >> 4) * 128, n0 = (wg & 15) * 192;

    f32x4 acc[2][6] = {};

    const int colswz = (g ^ (r & 7)) << 4;
    int vA[2], vB[6];
#pragma unroll
    for (int m = 0; m < 2; ++m)
        vA[m] = (wm * 32 + m * 16 + r) * 128 + colswz;               // + buf*16384; kk1 = ^64
#pragma unroll
    for (int j = 0; j < 6; ++j)
        vB[j] = 32768 + (wn * 96 + j * 16 + r) * 128 + colswz;       // + buf*24576
    const char* lds = (const char*)smem;

    const int lr = tid >> 3;                                    // 0..63
    const int scol = (((tid & 7) * 16) ^ ((lr & 7) << 4)) >> 1; // u16 units
    const u16* aS = A + (size_t)(m0 + lr) * 1024 + scol;
    const u16* bS = B + (size_t)(n0 + lr) * 1024 + scol;
    char* ldsT = (char*)smem + tid * 16;

    auto STAGE_ALL = [&](int buf, int t) {
        const u16* a = aS + t * 64;
        const u16* b = bS + t * 64;
        char* dA = ldsT + buf * 16384;
        char* dB = ldsT + 32768 + buf * 24576;
        async16(dA,          a);             // A rows   0..63
        async16(dA + 8192,   a + 65536);     // A rows  64..127
        async16(dB,          b);             // B rows   0..63
        async16(dB + 8192,   b + 65536);     // B rows  64..127
        async16(dB + 16384,  b + 131072);    // B rows 128..191
    };

    STAGE_ALL(0, 0);  // prologue

    for (int t = 0; t < 16; ++t) {
        const int buf = t & 1;
        if (t < 15) {
            STAGE_ALL(buf ^ 1, t + 1);
            asm volatile("s_waitcnt vmcnt(5)" ::: "memory");  // tile t landed; t+1 in flight
        } else {
            asm volatile("s_waitcnt vmcnt(0)" ::: "memory");
        }
        __builtin_amdgcn_s_barrier();
        asm volatile("" ::: "memory");

        bf16x8 a[2][2];
#pragma unroll
        for (int m = 0; m < 2; ++m) {
            int ad = buf * 16384 + vA[m];
            a[m][0] = *(const bf16x8*)(lds + ad);
            a[m][1] = *(const bf16x8*)(lds + (ad ^ 64));
        }
        __builtin_amdgcn_s_setprio(1);
#pragma unroll
        for (int j = 0; j < 6; ++j) {
            int bd = buf * 24576 + vB[j];
            bf16x8 b0 = *(const bf16x8*)(lds + bd);
            bf16x8 b1 = *(const bf16x8*)(lds + (bd ^ 64));
#pragma unroll
            for (int m = 0; m < 2; ++m) {
                acc[m][j] = __builtin_amdgcn_mfma_f32_16x16x32_bf16(a[m][0], b0, acc[m][j], 0, 0, 0);
                acc[m][j] = __builtin_amdgcn_mfma_f32_16x16x32_bf16(a[m][1], b1, acc[m][j], 0, 0, 0);
            }
        }
        __builtin_amdgcn_s_setprio(0);
        asm volatile("s_waitcnt lgkmcnt(0)" ::: "memory");  // reads done before next overwrite
        __builtin_amdgcn_s_barrier();
        asm volatile("" ::: "memory");
    }

    // ---- scatter epilogue. 3 col-pairs p: f = n0 + wn*96 + p*32; which constant/pair.
    // Q/K merged stores: the 8B-aligned adjacent pair is (wn==0 ? (0,1) : (1,2))
    // [byte offset of dv[p]*2 mod 8 == 0 exactly there]; merge when same which.
    int fvp[3], whp[3], dvp[3];
#pragma unroll
    for (int p = 0; p < 3; ++p) {
        fvp[p] = n0 + wn * 96 + p * 32;
        whp[p] = fvp[p] >> 10;
        dvp[p] = (fvp[p] & 1023) >> 4;
    }
    const int mp = wn;  // mergeable pair index (mp, mp+1)
    const int sp = wn ? 0 : 2;  // the lone pair
    const bool mergeOK = (whp[mp] < 2) && (whp[mp] == whp[mp + 1]);

    // V stores (unchanged: uint2 = 4 consecutive t per (h,d) row)
#pragma unroll
    for (int p = 0; p < 3; ++p) {
        if (whp[p] == 2) {
#pragma unroll
            for (int m = 0; m < 2; ++m) {
                int tt0 = m0 + wm * 32 + m * 16 + g * 4;
                int b = tt0 >> 11, t0 = tt0 & 2047;
#pragma unroll
                for (int dj = 0; dj < 2; ++dj) {
                    uint2 val;
                    val.x = pack2(acc[m][2 * p + dj][0], acc[m][2 * p + dj][1]);
                    val.y = pack2(acc[m][2 * p + dj][2], acc[m][2 * p + dj][3]);
                    *(uint2*)(Vtp + (((size_t)(b * 16 + r) * 64 + dvp[p] + dj) * 2048 + t0)) = val;
                }
            }
        }
    }

    // Q/K stores, per (m, reg) row with merged widths
#pragma unroll
    for (int m = 0; m < 2; ++m) {
#pragma unroll
        for (int reg = 0; reg < 4; ++reg) {
            int tt = m0 + wm * 32 + m * 16 + g * 4 + reg;
            int b = tt >> 11, t = tt & 2047;
            size_t rowO = ((size_t)(b * 16 + r) * 2048 + t) * 64;
            uint32_t w[3];
#pragma unroll
            for (int p = 0; p < 3; ++p) {
                float s = whp[p] ? 1.0f : QSCALE;
                w[p] = pack2(acc[m][2 * p][reg] * s, acc[m][2 * p + 1][reg] * s);
            }
            if (mergeOK) {
                u16* P = whp[mp] ? Kp : Qp;
                uint2 v2; v2.x = w[mp]; v2.y = w[mp + 1];
                *(uint2*)(P + rowO + dvp[mp]) = v2;
            } else {
                if (whp[mp] < 2)
                    *(uint32_t*)((whp[mp] ? Kp : Qp) + rowO + dvp[mp]) = w[mp];
                if (whp[mp + 1] < 2)
                    *(uint32_t*)((whp[mp + 1] ? Kp : Qp) + rowO + dvp[mp + 1]) = w[mp + 1];
            }
            if (whp[sp] < 2)
                *(uint32_t*)((whp[sp] ? Kp : Qp) + rowO + dvp[sp]) = w[sp];
        }
    }
}

// ============ out-proj GEMM: 128x128 tile, BK=64, 2-barrier/tile, f32 out ============
__global__ __launch_bounds__(512) void k_gemm_out(const u16* __restrict__ A,
                                                  const u16* __restrict__ B,
                                                  float* __restrict__ C) {
    __shared__ __align__(16) char smem[65536];
    const int tid = threadIdx.x;
    const int lane = tid & 63, wid = tid >> 6;
    const int r = lane & 15, g = lane >> 4;
    const int wm = wid >> 2, wn = wid & 3;
    const int lin = blockIdx.x;                    // 256 blocks
    const int wg = (lin & 7) * 32 + (lin >> 3);
    const int m0 = (wg >> 3) * 128, n0 = (wg & 7) * 128;

    f32x4 acc[4][2] = {};

    const int colswz = (g ^ (r & 7)) << 4;
    int vA[4], vB[2];
#pragma unroll
    for (int m = 0; m < 4; ++m) {
        int ii = wm * 64 + m * 16 + r;
        vA[m] = (ii >> 6) * 8192 + (ii & 63) * 128 + colswz;          // + buf*16384
    }
#pragma unroll
    for (int n = 0; n < 2; ++n) {
        int jj = wn * 32 + n * 16 + r;
        vB[n] = 32768 + (jj >> 6) * 8192 + (jj & 63) * 128 + colswz;  // + buf*16384
    }
    const char* lds = (const char*)smem;

    const int lr = tid >> 3;
    const int scol = (((tid & 7) * 16) ^ ((lr & 7) << 4)) >> 1;
    const u16* aS = A + (size_t)(m0 + lr) * 1024 + scol;
    const u16* bS = B + (size_t)(n0 + lr) * 1024 + scol;
    char* ldsT = (char*)smem + tid * 16;

    auto STAGE_ALL = [&](int buf, int t) {
        const u16* a = aS + t * 64;
        const u16* b = bS + t * 64;
        async16(ldsT + buf * 16384,          a);
        async16(ldsT + buf * 16384 + 8192,   a + 65536);
        async16(ldsT + 32768 + buf * 16384,        b);
        async16(ldsT + 32768 + buf * 16384 + 8192, b + 65536);
    };

    STAGE_ALL(0, 0);

    for (int t = 0; t < 16; ++t) {
        const int buf = t & 1;
        if (t < 15) {
            STAGE_ALL(buf ^ 1, t + 1);
            asm volatile("s_waitcnt vmcnt(4)" ::: "memory");
        } else {
            asm volatile("s_waitcnt vmcnt(0)" ::: "memory");
        }
        __builtin_amdgcn_s_barrier();
        asm volatile("" ::: "memory");

        bf16x8 a[4][2], b[2][2];
#pragma unroll
        for (int m = 0; m < 4; ++m) {
            int ad = buf * 16384 + vA[m];
            a[m][0] = *(const bf16x8*)(lds + ad);
            a[m][1] = *(const bf16x8*)(lds + (ad ^ 64));
        }
#pragma unroll
        for (int n = 0; n < 2; ++n) {
            int bd = buf * 16384 + vB[n];
            b[n][0] = *(const bf16x8*)(lds + bd);
            b[n][1] = *(const bf16x8*)(lds + (bd ^ 64));
        }
        __builtin_amdgcn_s_setprio(1);
#pragma unroll
        for (int m = 0; m < 4; ++m)
#pragma unroll
            for (int n = 0; n < 2; ++n) {
                acc[m][n] = __builtin_amdgcn_mfma_f32_16x16x32_bf16(a[m][0], b[n][0], acc[m][n], 0, 0, 0);
                acc[m][n] = __builtin_amdgcn_mfma_f32_16x16x32_bf16(a[m][1], b[n][1], acc[m][n], 0, 0, 0);
            }
        __builtin_amdgcn_s_setprio(0);
        asm volatile("s_waitcnt lgkmcnt(0)" ::: "memory");
        __builtin_amdgcn_s_barrier();
        asm volatile("" ::: "memory");
    }

#pragma unroll
    for (int m = 0; m < 4; ++m) {
#pragma unroll
        for (int reg = 0; reg < 4; ++reg) {
            size_t crow = (size_t)(m0 + wm * 64 + m * 16 + g * 4 + reg);
#pragma unroll
            for (int n = 0; n < 2; ++n)
                C[crow * 1024 + n0 + wn * 32 + n * 16 + r] = acc[m][n][reg];
        }
    }
}

// ---------------- flash attention: 8 warps x 32 q-rows, K prefetch-2 / V prefetch-1 ----
// Q pre-scaled -> P = exp2(S). Row-sum via MFMA(ones, P). K 4-buf (write (t+2)&3),
// V 4-buf (write (t+1)&3); safe under <=1-iter wave skew (disjoint mod-4 distances).
// vmcnt by queue simulation: steady 4; tail 4/4/3/1; 0 before final PV.
__global__ __launch_bounds__(512, 1) void k_attn(const u16* __restrict__ Qp,
                                                 const u16* __restrict__ Kp,
                                                 const u16* __restrict__ Vtp,
                                                 u16* __restrict__ O) {
    constexpr int T = 2048;
    // K0..K3 @ 0,8192,16384,24576 | V0..V3 @ 32768,40960,49152,57344
    __shared__ __align__(16) char smem[65536];

    const int tid = threadIdx.x;
    const int lane = tid & 63, wv = tid >> 6;
    const int l31 = lane & 31, hi = lane >> 5;

    const int lin = blockIdx.x;
    const int work = (lin & 7) * 32 + (lin >> 3);
    const int bh = work >> 3, qchunk = work & 7;
    const int q0 = qchunk * 256 + wv * 32;

    const u16* Qb = Qp + (size_t)bh * T * 64;
    const u16* Kb = Kp + (size_t)bh * T * 64;
    const u16* Vb = Vtp + (size_t)bh * 64 * T;

    const u16* qrow = Qb + (size_t)(q0 + l31) * 64 + hi * 8;
    bf16x8 qf[4];
#pragma unroll
    for (int kb = 0; kb < 4; ++kb) qf[kb] = *(const bf16x8*)(qrow + kb * 16);

    const char* ldsB = (const char*)smem;
    int off[4];
#pragma unroll
    for (int s = 0; s < 4; ++s)
        off[s] = l31 * 128 + ((((2 * s + hi) ^ (l31 & 7))) << 4);

    const int srow = tid >> 3;                                   // 0..63
    const int scol = (((tid & 7) * 16) ^ ((srow & 7) << 4)) >> 1;
    const u16* kSrc = Kb + srow * 64 + scol;
    const u16* vSrc = Vb + (size_t)srow * T + scol;
    char* ldsT = smem + tid * 16;

    u32x4 onesu; onesu.x = 0x3F803F80u; onesu.y = 0x3F803F80u;
    onesu.z = 0x3F803F80u; onesu.w = 0x3F803F80u;
    const bf16x8 ones8 = __builtin_bit_cast(bf16x8, onesu);

    f32x16 st[2], oa[2], ls;
    f32x16 z;
#pragma unroll
    for (int e = 0; e < 16; ++e) { z[e] = 0.f; oa[0][e] = 0.f; oa[1][e] = 0.f; ls[e] = 0.f; }
    bf16x8 pf[4] = {};

    // compute body for tile it: QK from KB, PV(it-1)+sum from VBprev, exp, pack
    auto body = [&](int KB, int VBprev, bool dopv) {
        __builtin_amdgcn_s_setprio(1);
        {
            bf16x8 k0 = *(const bf16x8*)(ldsB + off[0] + KB);
            bf16x8 k1 = *(const bf16x8*)(ldsB + off[0] + KB + 4096);
            st[0] = __builtin_amdgcn_mfma_f32_32x32x16_bf16(k0, qf[0], z, 0, 0, 0);
            st[1] = __builtin_amdgcn_mfma_f32_32x32x16_bf16(k1, qf[0], z, 0, 0, 0);
        }
#pragma unroll
        for (int kb = 1; kb < 4; ++kb) {
            bf16x8 k0 = *(const bf16x8*)(ldsB + off[kb] + KB);
            bf16x8 k1 = *(const bf16x8*)(ldsB + off[kb] + KB + 4096);
            st[0] = __builtin_amdgcn_mfma_f32_32x32x16_bf16(k0, qf[kb], st[0], 0, 0, 0);
            st[1] = __builtin_amdgcn_mfma_f32_32x32x16_bf16(k1, qf[kb], st[1], 0, 0, 0);
        }
        if (dopv) {
#pragma unroll
            for (int jk = 0; jk < 4; ++jk) {
                bf16x8 v0 = *(const bf16x8*)(ldsB + off[jk] + VBprev);
                bf16x8 v1 = *(const bf16x8*)(ldsB + off[jk] + VBprev + 4096);
                oa[0] = __builtin_amdgcn_mfma_f32_32x32x16_bf16(v0, pf[jk], oa[0], 0, 0, 0);
                oa[1] = __builtin_amdgcn_mfma_f32_32x32x16_bf16(v1, pf[jk], oa[1], 0, 0, 0);
                ls    = __builtin_amdgcn_mfma_f32_32x32x16_bf16(ones8, pf[jk], ls, 0, 0, 0);
            }
        }
        __builtin_amdgcn_s_setprio(0);

#pragma unroll
        for (int tt = 0; tt < 2; ++tt)
#pragma unroll
            for (int e = 0; e < 16; ++e)
                st[tt][e] = exp2r(st[tt][e]);

#pragma unroll
        for (int t2 = 0; t2 < 2; ++t2) {
            uint32_t c0 = cvtpk(st[t2][0], st[t2][1]);
            uint32_t c1 = cvtpk(st[t2][2], st[t2][3]);
            uint32_t c2 = cvtpk(st[t2][4], st[t2][5]);
            uint32_t c3 = cvtpk(st[t2][6], st[t2][7]);
            uint32_t c4 = cvtpk(st[t2][8], st[t2][9]);
            uint32_t c5 = cvtpk(st[t2][10], st[t2][11]);
            uint32_t c6 = cvtpk(st[t2][12], st[t2][13]);
            uint32_t c7 = cvtpk(st[t2][14], st[t2][15]);
            u32x2v s0 = __builtin_amdgcn_permlane32_swap(c0, c2, false, false);
            u32x2v s1 = __builtin_amdgcn_permlane32_swap(c1, c3, false, false);
            u32x2v s2 = __builtin_amdgcn_permlane32_swap(c4, c6, false, false);
            u32x2v s3 = __builtin_amdgcn_permlane32_swap(c5, c7, false, false);
            u32x4 f0; f0.x = s0[0]; f0.y = s1[0]; f0.z = s0[1]; f0.w = s1[1];
            u32x4 f1; f1.x = s2[0]; f1.y = s3[0]; f1.z = s2[1]; f1.w = s3[1];
            pf[2 * t2]     = __builtin_bit_cast(bf16x8, f0);
            pf[2 * t2 + 1] = __builtin_bit_cast(bf16x8, f1);
        }
        asm volatile("" ::: "memory");
    };

    // prologue: K0 -> Kbuf0, V0 -> Vbuf0, K1 -> Kbuf1  (queue: [K0, V0, K1])
    async16(ldsT, kSrc);
    async16(ldsT + 32768, vSrc);
    async16(ldsT + 8192, kSrc + 4096);

    // main loop: it = 0..27. stage K(it+2) -> (it+2)&3, V(it+1) -> (it+1)&3; vmcnt(4).
    for (int it4 = 0; it4 < 7; ++it4) {
#pragma unroll
        for (int sub = 0; sub < 4; ++sub) {
            const int it = it4 * 4 + sub;
            const int KB = sub * 8192;
            const int VBprev = 32768 + ((sub + 3) & 3) * 8192;
            async16(ldsT + ((sub + 2) & 3) * 8192, kSrc + (size_t)(it + 2) * 4096);
            async16(ldsT + 32768 + ((sub + 1) & 3) * 8192, vSrc + (it + 1) * 64);
            asm volatile("s_waitcnt vmcnt(4)" ::: "memory");
            __builtin_amdgcn_s_barrier();
            asm volatile("" ::: "memory");
            body(KB, VBprev, it != 0);
        }
    }

    // tail: it = 28..31 (peeled; vmcnt by queue simulation)
    async16(ldsT + 16384, kSrc + (size_t)30 * 4096);
    async16(ldsT + 32768 + 8192, vSrc + 29 * 64);
    asm volatile("s_waitcnt vmcnt(4)" ::: "memory");
    __builtin_amdgcn_s_barrier();
    asm volatile("" ::: "memory");
    body(0, 32768 + 24576, true);
    async16(ldsT + 24576, kSrc + (size_t)31 * 4096);
    async16(ldsT + 32768 + 16384, vSrc + 30 * 64);
    asm volatile("s_waitcnt vmcnt(4)" ::: "memory");
    __builtin_amdgcn_s_barrier();
    asm volatile("" ::: "memory");
    body(8192, 32768, true);
    async16(ldsT + 32768 + 24576, vSrc + 31 * 64);
    asm volatile("s_waitcnt vmcnt(3)" ::: "memory");
    __builtin_amdgcn_s_barrier();
    asm volatile("" ::: "memory");
    body(16384, 32768 + 8192, true);
    asm volatile("s_waitcnt vmcnt(1)" ::: "memory");
    __builtin_amdgcn_s_barrier();
    asm volatile("" ::: "memory");
    body(24576, 32768 + 16384, true);

    // final PV(31): V31 in Vbuf3
    asm volatile("s_waitcnt vmcnt(0)" ::: "memory");
    __builtin_amdgcn_s_barrier();
    asm volatile("" ::: "memory");
#pragma unroll
    for (int jk = 0; jk < 4; ++jk) {
        bf16x8 v0 = *(const bf16x8*)(ldsB + off[jk] + 57344);
        bf16x8 v1 = *(const bf16x8*)(ldsB + off[jk] + 57344 + 4096);
        oa[0] = __builtin_amdgcn_mfma_f32_32x32x16_bf16(v0, pf[jk], oa[0], 0, 0, 0);
        oa[1] = __builtin_amdgcn_mfma_f32_32x32x16_bf16(v1, pf[jk], oa[1], 0, 0, 0);
        ls    = __builtin_amdgcn_mfma_f32_32x32x16_bf16(ones8, pf[jk], ls, 0, 0, 0);
    }

    // epilogue: ls[0] = full row sum for q-col l31
    float linv = 1.0f / ls[0];
    const int b = bh >> 4, h = bh & 15;
    u16* obase = O + ((size_t)b * T + q0 + l31) * 1024 + h * 64 + 4 * hi;
#pragma unroll
    for (int q = 0; q < 8; ++q) {
        int dbase = ((2 * q) & 3) + 8 * (q >> 1);
        *(uint32_t*)(obase + dbase)      = pack2(oa[0][2 * q] * linv, oa[0][2 * q + 1] * linv);
        *(uint32_t*)(obase + 32 + dbase) = pack2(oa[1][2 * q] * linv, oa[1][2 * q + 1] * linv);
    }
}

extern "C" void kernel_launch(void* const* d_in, const int* in_sizes, int n_in,
                              void* d_out, int out_size, void* d_ws, size_t ws_size,
                              hipStream_t stream) {
    const float* x    = (const float*)d_in[0];  // [2,2048,1024]
    const float* wqkv = (const float*)d_in[1];  // [3072,1024]
    const float* wout = (const float*)d_in[2];  // [1024,1024]
    float* out = (float*)d_out;
    char* ws = (char*)d_ws;

    u16* xb   = (u16*)(ws);                    //  8,388,608 B
    u16* wqb  = (u16*)(ws + 8388608);          //  6,291,456
    u16* wob  = (u16*)(ws + 14680064);         //  2,097,152
    u16* Qp   = (u16*)(ws + 41943040);         //  8,388,608
    u16* Kp   = (u16*)(ws + 50331648);         //  8,388,608
    u16* Vtp  = (u16*)(ws + 58720256);         //  8,388,608
    u16* Ob   = (u16*)(ws + 67108864);         //  8,388,608

    k_cvt3<<<4096, 256, 0, stream>>>(x, wqkv, wout, xb, wqb, wob);
    k_gemm_qkv<<<dim3(512), 512, 0, stream>>>(xb, wqb, Qp, Kp, Vtp);
    k_attn<<<dim3(256), dim3(512), 0, stream>>>(Qp, Kp, Vtp, Ob);
    k_gemm_out<<<dim3(256), 512, 0, stream>>>(Ob, wob, out);
}